// Round 1
// baseline (487.556 us; speedup 1.0000x reference)
//
#include <hip/hip_runtime.h>

#define EPS 1e-5f
typedef unsigned short u16;
typedef unsigned int u32;

// ---------- bf16 helpers ----------
__device__ __forceinline__ float bf2f(u16 h) {
    u32 u = ((u32)h) << 16;
    return __builtin_bit_cast(float, u);
}
__device__ __forceinline__ u16 f2bf(float f) {
    u32 u = __builtin_bit_cast(u32, f);
    u32 r = (u + 0x7fffu + ((u >> 16) & 1u)) >> 16;   // RNE
    return (u16)r;
}

// ============================================================
// K1: qkv[n,o,l] = sum_c W[o,c] * x[b,c,h,l]   (n = b*64+h)
//     + per-channel (o) sum/sumsq accumulation for BN stats
// grid (4, 128): ot = o-tile of 64, n. block 256.
// ============================================================
__global__ __launch_bounds__(256) void k1_gemm_qkv(
    const float* __restrict__ x, const float* __restrict__ Wq,
    float* __restrict__ qkv, float* __restrict__ stats)
{
    __shared__ float Wt[64 * 68];    // padded stride 68
    __shared__ float xt[64 * 128];
    const int tid = threadIdx.x;
    const int ot = blockIdx.x;           // 0..3
    const int n  = blockIdx.y;           // 0..127
    const int b = n >> 6, h = n & 63;
    const int to = tid >> 5, tl = tid & 31;
    const int o0 = to * 8, l0 = tl * 4;

    float acc[8][4];
#pragma unroll
    for (int r = 0; r < 8; ++r) { acc[r][0]=0.f; acc[r][1]=0.f; acc[r][2]=0.f; acc[r][3]=0.f; }

    for (int cb = 0; cb < 128; cb += 64) {
        __syncthreads();
#pragma unroll
        for (int k = 0; k < 4; ++k) {
            int f = tid + k * 256;            // < 1024
            int oo = f >> 4, c4 = f & 15;
            float4 v = *(const float4*)(Wq + (ot * 64 + oo) * 128 + cb + c4 * 4);
            *(float4*)(Wt + oo * 68 + c4 * 4) = v;
        }
#pragma unroll
        for (int k = 0; k < 8; ++k) {
            int f = tid + k * 256;            // < 2048
            int c = f >> 5, l4 = f & 31;
            float4 v = *(const float4*)(x + ((size_t)((b * 128 + cb + c) * 64 + h)) * 128 + l4 * 4);
            *(float4*)(xt + c * 128 + l4 * 4) = v;
        }
        __syncthreads();
#pragma unroll 4
        for (int c = 0; c < 64; ++c) {
            float4 xv = *(const float4*)(xt + c * 128 + l0);
#pragma unroll
            for (int r = 0; r < 8; ++r) {
                float w = Wt[(o0 + r) * 68 + c];
                acc[r][0] += w * xv.x; acc[r][1] += w * xv.y;
                acc[r][2] += w * xv.z; acc[r][3] += w * xv.w;
            }
        }
    }

#pragma unroll
    for (int r = 0; r < 8; ++r) {
        int o = ot * 64 + o0 + r;
        *(float4*)(qkv + ((size_t)n * 256 + o) * 128 + l0) =
            make_float4(acc[r][0], acc[r][1], acc[r][2], acc[r][3]);
        float s  = acc[r][0] + acc[r][1] + acc[r][2] + acc[r][3];
        float sq = acc[r][0]*acc[r][0] + acc[r][1]*acc[r][1] + acc[r][2]*acc[r][2] + acc[r][3]*acc[r][3];
#pragma unroll
        for (int m = 1; m < 32; m <<= 1) {   // reduce over the 32 tl lanes
            s  += __shfl_xor(s, m);
            sq += __shfl_xor(sq, m);
        }
        if (tl == 0) {
            atomicAdd(&stats[o], s);
            atomicAdd(&stats[256 + o], sq);
        }
    }
}

// ============================================================
// K3: BN coefs for qkv (256 channels over 128*128 samples)
// ============================================================
__global__ void k3_coef_qkv(const float* __restrict__ stats,
                            const float* __restrict__ gamma, const float* __restrict__ beta,
                            float* __restrict__ coef)
{
    int o = threadIdx.x;               // 256 threads
    const float cnt = 16384.f;
    float mean = stats[o] / cnt;
    float var  = stats[256 + o] / cnt - mean * mean;
    float a = gamma[o] * rsqrtf(var + EPS);
    coef[o] = a;
    coef[256 + o] = beta[o] - a * mean;
}

// ============================================================
// K4 (pass 1): per (n,g) build QE,KE in LDS, qk = QE^T*KE -> bf16 global,
//              accumulate sim BN stats (qe/ke/qk sum & sumsq per g).
// grid 2048 (n*16+g), block 256. LDS ~140 KB -> 1 WG/CU.
// ============================================================
__global__ __launch_bounds__(256, 1) void k4_pass1(
    const float* __restrict__ qkv, const float* __restrict__ rel,
    const float* __restrict__ cq, u16* __restrict__ qk,
    float* __restrict__ stats)
{
    __shared__ float QE[128 * 128];
    __shared__ float KE[128 * 128];
    __shared__ float qn[1024];      // [0..511] q rows 0..3, [512..1023] k rows 0..3
    __shared__ float relq[8 * 256]; // rel rows 0..7, padded stride 256
    __shared__ float red[24];
    const int tid = threadIdx.x;
    const int n = blockIdx.x >> 4, g = blockIdx.x & 15;

#pragma unroll
    for (int k = 0; k < 8; ++k)
        if (tid < 255) relq[k * 256 + tid] = rel[k * 255 + tid];
#pragma unroll
    for (int k = 0; k < 4; ++k) {
        int f = tid + k * 256;          // < 1024
        int row = f >> 7, t = f & 127;
        int o = g * 16 + row;
        qn[f] = cq[o] * qkv[((size_t)n * 256 + o) * 128 + t] + cq[256 + o];
    }
    __syncthreads();

    float qes = 0.f, qesq = 0.f, kes = 0.f, kesq = 0.f;
#pragma unroll 4
    for (int k = 0; k < 64; ++k) {
        int e = tid + k * 256;
        int t = e >> 7, i = e & 127;
        int d = t - i + 127;
        float qv = qn[t]       * relq[d]        + qn[128 + t] * relq[256 + d]
                 + qn[256 + t] * relq[512 + d]  + qn[384 + t] * relq[768 + d];
        QE[t * 128 + i] = qv; qes += qv; qesq += qv * qv;
        float kv = qn[512 + t] * relq[1024 + d] + qn[640 + t] * relq[1280 + d]
                 + qn[768 + t] * relq[1536 + d] + qn[896 + t] * relq[1792 + d];
        KE[t * 128 + i] = kv; kes += kv; kesq += kv * kv;
    }
    __syncthreads();

    // 8x8 register-tiled matmul: qk[i,j] = sum_t QE[t,i]*KE[t,j]
    const int ti = tid >> 4, tj = tid & 15;
    const int i0 = ti * 8, j0 = tj * 8;
    float acc[8][8];
#pragma unroll
    for (int r = 0; r < 8; ++r)
#pragma unroll
        for (int c = 0; c < 8; ++c) acc[r][c] = 0.f;

#pragma unroll 2
    for (int t = 0; t < 128; ++t) {
        float4 a0 = *(const float4*)(QE + t * 128 + i0);
        float4 a1 = *(const float4*)(QE + t * 128 + i0 + 4);
        float4 b0 = *(const float4*)(KE + t * 128 + j0);
        float4 b1 = *(const float4*)(KE + t * 128 + j0 + 4);
        float av[8] = {a0.x,a0.y,a0.z,a0.w,a1.x,a1.y,a1.z,a1.w};
        float bv[8] = {b0.x,b0.y,b0.z,b0.w,b1.x,b1.y,b1.z,b1.w};
#pragma unroll
        for (int r = 0; r < 8; ++r)
#pragma unroll
            for (int c = 0; c < 8; ++c) acc[r][c] += av[r] * bv[c];
    }

    float qks = 0.f, qksq = 0.f;
#pragma unroll
    for (int r = 0; r < 8; ++r) {
        u32 u[4];
#pragma unroll
        for (int c2 = 0; c2 < 4; ++c2) {
            u[c2] = (u32)f2bf(acc[r][2 * c2]) | ((u32)f2bf(acc[r][2 * c2 + 1]) << 16);
        }
        *(uint4*)(qk + ((size_t)(n * 16 + g) * 128 + i0 + r) * 128 + j0) =
            make_uint4(u[0], u[1], u[2], u[3]);
#pragma unroll
        for (int c = 0; c < 8; ++c) { qks += acc[r][c]; qksq += acc[r][c] * acc[r][c]; }
    }

    // reduce 6 partials over each wave, then across 4 waves via LDS
#pragma unroll
    for (int m = 1; m < 64; m <<= 1) {
        qes += __shfl_xor(qes, m);  qesq += __shfl_xor(qesq, m);
        kes += __shfl_xor(kes, m);  kesq += __shfl_xor(kesq, m);
        qks += __shfl_xor(qks, m);  qksq += __shfl_xor(qksq, m);
    }
    if ((tid & 63) == 0) {
        int wv = tid >> 6;
        red[wv * 6 + 0] = qes; red[wv * 6 + 1] = qesq;
        red[wv * 6 + 2] = kes; red[wv * 6 + 3] = kesq;
        red[wv * 6 + 4] = qks; red[wv * 6 + 5] = qksq;
    }
    __syncthreads();
    if (tid < 6) {
        float tot = red[tid] + red[6 + tid] + red[12 + tid] + red[18 + tid];
        int off = (tid & 1) ? 560 : 512;                    // sum vs sumsq base
        int ch = (tid < 2) ? (16 + g) : (tid < 4) ? (32 + g) : g;  // qe / ke / qk
        atomicAdd(&stats[off + ch], tot);
    }
}

// ============================================================
// K5: BN coefs for sim (48 channels over 128*128*128 samples)
// ============================================================
__global__ void k5_coef_sim(const float* __restrict__ stats,
                            const float* __restrict__ gamma, const float* __restrict__ beta,
                            float* __restrict__ coef)
{
    int ch = threadIdx.x;
    if (ch < 48) {
        const float cnt = 2097152.f;
        float mean = stats[512 + ch] / cnt;
        float var  = stats[560 + ch] / cnt - mean * mean;
        float a = gamma[ch] * rsqrtf(var + EPS);
        coef[ch] = a;
        coef[48 + ch] = beta[ch] - a * mean;
    }
}

// ============================================================
// K6 (pass 2): per (n,g): sim rows = a_qk*qk + a_qe*qe + a_ke*ke + b,
// softmax over j, am = P*v^T, ame = P (*) v_emb, write outraw + out stats.
// 16 lanes per row, 4 rows per wave. grid 2048, block 256.
// ============================================================
__global__ __launch_bounds__(256, 2) void k6_pass2(
    const float* __restrict__ qkv, const float* __restrict__ rel,
    const float* __restrict__ cq, const float* __restrict__ cs,
    const u16* __restrict__ qk,
    float* __restrict__ outraw, float* __restrict__ ostats)
{
    __shared__ float relT[255 * 20];  // relT[d*20 + c] = rel[c][d], padded stride 20
    __shared__ float qv_s[2048];      // q rows(0..511), k rows(512..1023), v rows(1024..2047)
    __shared__ float ot_s[16 * 132];  // out tile [ch16][i], padded stride 132
    const int tid = threadIdx.x;
    const int n = blockIdx.x >> 4, g = blockIdx.x & 15;

#pragma unroll
    for (int k = 0; k < 16; ++k) {
        int f = tid + k * 256;        // < 4096
        int d = f >> 4, c = f & 15;
        if (d < 255) relT[d * 20 + c] = rel[c * 255 + d];
    }
#pragma unroll
    for (int k = 0; k < 8; ++k) {
        int f = tid + k * 256;        // < 2048
        int row = f >> 7, t = f & 127;
        int o = g * 16 + row;
        qv_s[f] = cq[o] * qkv[((size_t)n * 256 + o) * 128 + t] + cq[256 + o];
    }
    __syncthreads();

    const float aqk = cs[g], aqe = cs[16 + g], ake = cs[32 + g];
    const float bsum = cs[48 + g] + cs[64 + g] + cs[80 + g];
    const int lane = tid & 63, wv = tid >> 6;
    const int r = lane >> 4, q = lane & 15;

    // cache this lane's v columns: v[c][j] for j = q + 16*jj
    float vreg[8][8];
#pragma unroll
    for (int jj = 0; jj < 8; ++jj) {
        int j = q + 16 * jj;
#pragma unroll
        for (int c = 0; c < 8; ++c) vreg[jj][c] = qv_s[1024 + c * 128 + j];
    }
    const u16* qkg = qk + (size_t)(n * 16 + g) * 16384;

    for (int it = 0; it < 8; ++it) {
        int i = wv * 32 + it * 4 + r;
        float q0 = qv_s[i], q1 = qv_s[128 + i], q2 = qv_s[256 + i], q3 = qv_s[384 + i];
        float k0 = qv_s[512 + i], k1 = qv_s[640 + i], k2 = qv_s[768 + i], k3 = qv_s[896 + i];
        const u16* qkrow = qkg + i * 128;
        float s[8]; float mx = -3.0e38f;
#pragma unroll
        for (int jj = 0; jj < 8; ++jj) {
            int j = q + 16 * jj;
            int d = i - j + 127;
            float4 rq = *(const float4*)(relT + d * 20);
            float4 rk = *(const float4*)(relT + d * 20 + 4);
            float qe = q0 * rq.x + q1 * rq.y + q2 * rq.z + q3 * rq.w;
            float ke = k0 * rk.x + k1 * rk.y + k2 * rk.z + k3 * rk.w;
            float qkf = bf2f(qkrow[j]);
            float sv = aqk * qkf + aqe * qe + ake * ke + bsum;
            s[jj] = sv; mx = fmaxf(mx, sv);
        }
#pragma unroll
        for (int m = 1; m < 16; m <<= 1) mx = fmaxf(mx, __shfl_xor(mx, m));
        float es = 0.f; float e[8];
#pragma unroll
        for (int jj = 0; jj < 8; ++jj) { e[jj] = __expf(s[jj] - mx); es += e[jj]; }
#pragma unroll
        for (int m = 1; m < 16; m <<= 1) es += __shfl_xor(es, m);

        float am[8], ame[8];
#pragma unroll
        for (int c = 0; c < 8; ++c) { am[c] = 0.f; ame[c] = 0.f; }
#pragma unroll
        for (int jj = 0; jj < 8; ++jj) {
            int d = i - (q + 16 * jj) + 127;
            float4 r0 = *(const float4*)(relT + d * 20 + 8);
            float4 r1 = *(const float4*)(relT + d * 20 + 12);
            float ej = e[jj];
#pragma unroll
            for (int c = 0; c < 8; ++c) am[c] += ej * vreg[jj][c];
            ame[0] += ej * r0.x; ame[1] += ej * r0.y; ame[2] += ej * r0.z; ame[3] += ej * r0.w;
            ame[4] += ej * r1.x; ame[5] += ej * r1.y; ame[6] += ej * r1.z; ame[7] += ej * r1.w;
        }
#pragma unroll
        for (int m = 1; m < 16; m <<= 1) {
#pragma unroll
            for (int c = 0; c < 8; ++c) {
                am[c]  += __shfl_xor(am[c], m);
                ame[c] += __shfl_xor(ame[c], m);
            }
        }
        float inv = 1.f / es;
        float sel = 0.f;
#pragma unroll
        for (int c = 0; c < 8; ++c) {
            sel = (q == c)     ? am[c]  : sel;
            sel = (q == c + 8) ? ame[c] : sel;
        }
        int ch16 = (q < 8) ? (2 * q) : (2 * (q - 8) + 1);
        ot_s[ch16 * 132 + i] = sel * inv;
    }
    __syncthreads();

    // write out tile + out BN stats
#pragma unroll
    for (int k = 0; k < 8; ++k) {
        int f = tid + k * 256;
        int ch16 = f >> 7, i = f & 127;     // ch16 is wave-uniform
        float v = ot_s[ch16 * 132 + i];
        outraw[((size_t)n * 256 + g * 16 + ch16) * 128 + i] = v;
        float sv = v, sq = v * v;
#pragma unroll
        for (int m = 1; m < 64; m <<= 1) { sv += __shfl_xor(sv, m); sq += __shfl_xor(sq, m); }
        if (lane == 0) {
            atomicAdd(&ostats[g * 16 + ch16], sv);
            atomicAdd(&ostats[256 + g * 16 + ch16], sq);
        }
    }
}

// ============================================================
// K7: BN coefs for out (256 channels over 128*128 samples)
// ============================================================
__global__ void k7_coef_out(const float* __restrict__ stats,
                            const float* __restrict__ gamma, const float* __restrict__ beta,
                            float* __restrict__ coef)
{
    int o = threadIdx.x;
    const float cnt = 16384.f;
    float mean = stats[608 + o] / cnt;
    float var  = stats[864 + o] / cnt - mean * mean;
    float a = gamma[o] * rsqrtf(var + EPS);
    coef[o] = a;
    coef[256 + o] = beta[o] - a * mean;
}

// ============================================================
// K8: final[b,oc,h,w] = bn(outraw[n,2oc,w]) + bn(outraw[n,2oc+1,w])
// ============================================================
__global__ __launch_bounds__(256) void k8_final(
    const float* __restrict__ outraw, const float* __restrict__ co,
    float* __restrict__ out)
{
    int idx = blockIdx.x * 256 + threadIdx.x;   // < 2097152
    int w  = idx & 127;
    int h  = (idx >> 7) & 63;
    int oc = (idx >> 13) & 127;
    int b  = idx >> 20;
    int n  = b * 64 + h;
    int o0 = oc * 2;
    float x0 = outraw[((size_t)n * 256 + o0) * 128 + w];
    float x1 = outraw[((size_t)n * 256 + o0 + 1) * 128 + w];
    out[idx] = (co[o0] * x0 + co[256 + o0]) + (co[o0 + 1] * x1 + co[256 + o0 + 1]);
}

// ============================================================
// Workspace layout (floats):
//   qkv    @ 0          : 4,194,304
//   outraw @ 4,194,304  : 4,194,304
//   qk bf16@ 8,388,608  : 33,554,432 u16 (= 16,777,216 float slots)
//   stats  @ 25,165,824 :
//     [0..255] qkv sum, [256..511] qkv sumsq
//     [512..559] sim sum, [560..607] sim sumsq
//     [608..863] out sum, [864..1119] out sumsq     (zeroed each call)
//     [1120..1631] cq (a,b), [1632..1727] cs (a,b), [1728..2239] co (a,b)
//  total ~96 MB
// ============================================================
extern "C" void kernel_launch(void* const* d_in, const int* in_sizes, int n_in,
                              void* d_out, int out_size, void* d_ws, size_t ws_size,
                              hipStream_t stream)
{
    const float* x   = (const float*)d_in[0];
    const float* Wq  = (const float*)d_in[1];
    const float* gq  = (const float*)d_in[2];
    const float* bq  = (const float*)d_in[3];
    const float* rel = (const float*)d_in[4];
    const float* gs  = (const float*)d_in[5];
    const float* bs  = (const float*)d_in[6];
    const float* go  = (const float*)d_in[7];
    const float* bo  = (const float*)d_in[8];

    float* ws     = (float*)d_ws;
    float* qkv    = ws;
    float* outraw = ws + 4194304;
    u16*   qk     = (u16*)(ws + 8388608);
    float* stats  = ws + 25165824;
    float* cq     = stats + 1120;
    float* cs     = stats + 1632;
    float* co     = stats + 1728;

    hipMemsetAsync(stats, 0, 1120 * sizeof(float), stream);

    k1_gemm_qkv<<<dim3(4, 128), 256, 0, stream>>>(x, Wq, qkv, stats);
    k3_coef_qkv<<<1, 256, 0, stream>>>(stats, gq, bq, cq);
    k4_pass1<<<2048, 256, 0, stream>>>(qkv, rel, cq, qk, stats);
    k5_coef_sim<<<1, 64, 0, stream>>>(stats, gs, bs, cs);
    k6_pass2<<<2048, 256, 0, stream>>>(qkv, rel, cq, cs, qk, outraw, stats + 608);
    k7_coef_out<<<1, 256, 0, stream>>>(stats, go, bo, co);
    k8_final<<<8192, 256, 0, stream>>>(outraw, co, (float*)d_out);
}

// Round 3
// 475.407 us; speedup vs baseline: 1.0256x; 1.0256x over previous
//
#include <hip/hip_runtime.h>

#define EPS 1e-5f
typedef unsigned short u16;
typedef unsigned int u32;

typedef __attribute__((ext_vector_type(8))) short bf16x8;
typedef __attribute__((ext_vector_type(4))) float f32x4;

// ---------- bf16 helpers ----------
__device__ __forceinline__ float bf2f(u16 h) {
    u32 u = ((u32)h) << 16;
    return __builtin_bit_cast(float, u);
}
__device__ __forceinline__ u16 f2bf(float f) {
    u32 u = __builtin_bit_cast(u32, f);
    u32 r = (u + 0x7fffu + ((u >> 16) & 1u)) >> 16;   // RNE
    return (u16)r;
}
__device__ __forceinline__ u32 pack2(float a, float b) {
    return (u32)f2bf(a) | ((u32)f2bf(b) << 16);
}

// ============================================================
// K1: qkv[n,o,l] = sum_c W[o,c] * x[b,c,h,l]   (n = b*64+h)
//     + per-channel (o) sum/sumsq accumulation for BN stats
// ============================================================
__global__ __launch_bounds__(256) void k1_gemm_qkv(
    const float* __restrict__ x, const float* __restrict__ Wq,
    float* __restrict__ qkv, float* __restrict__ stats)
{
    __shared__ float Wt[64 * 68];
    __shared__ float xt[64 * 128];
    const int tid = threadIdx.x;
    const int ot = blockIdx.x;
    const int n  = blockIdx.y;
    const int b = n >> 6, h = n & 63;
    const int to = tid >> 5, tl = tid & 31;
    const int o0 = to * 8, l0 = tl * 4;

    float acc[8][4];
#pragma unroll
    for (int r = 0; r < 8; ++r) { acc[r][0]=0.f; acc[r][1]=0.f; acc[r][2]=0.f; acc[r][3]=0.f; }

    for (int cb = 0; cb < 128; cb += 64) {
        __syncthreads();
#pragma unroll
        for (int k = 0; k < 4; ++k) {
            int f = tid + k * 256;
            int oo = f >> 4, c4 = f & 15;
            float4 v = *(const float4*)(Wq + (ot * 64 + oo) * 128 + cb + c4 * 4);
            *(float4*)(Wt + oo * 68 + c4 * 4) = v;
        }
#pragma unroll
        for (int k = 0; k < 8; ++k) {
            int f = tid + k * 256;
            int c = f >> 5, l4 = f & 31;
            float4 v = *(const float4*)(x + ((size_t)((b * 128 + cb + c) * 64 + h)) * 128 + l4 * 4);
            *(float4*)(xt + c * 128 + l4 * 4) = v;
        }
        __syncthreads();
#pragma unroll 4
        for (int c = 0; c < 64; ++c) {
            float4 xv = *(const float4*)(xt + c * 128 + l0);
#pragma unroll
            for (int r = 0; r < 8; ++r) {
                float w = Wt[(o0 + r) * 68 + c];
                acc[r][0] += w * xv.x; acc[r][1] += w * xv.y;
                acc[r][2] += w * xv.z; acc[r][3] += w * xv.w;
            }
        }
    }

#pragma unroll
    for (int r = 0; r < 8; ++r) {
        int o = ot * 64 + o0 + r;
        *(float4*)(qkv + ((size_t)n * 256 + o) * 128 + l0) =
            make_float4(acc[r][0], acc[r][1], acc[r][2], acc[r][3]);
        float s  = acc[r][0] + acc[r][1] + acc[r][2] + acc[r][3];
        float sq = acc[r][0]*acc[r][0] + acc[r][1]*acc[r][1] + acc[r][2]*acc[r][2] + acc[r][3]*acc[r][3];
#pragma unroll
        for (int m = 1; m < 32; m <<= 1) {
            s  += __shfl_xor(s, m);
            sq += __shfl_xor(sq, m);
        }
        if (tl == 0) {
            atomicAdd(&stats[o], s);
            atomicAdd(&stats[256 + o], sq);
        }
    }
}

__global__ void k3_coef_qkv(const float* __restrict__ stats,
                            const float* __restrict__ gamma, const float* __restrict__ beta,
                            float* __restrict__ coef)
{
    int o = threadIdx.x;
    const float cnt = 16384.f;
    float mean = stats[o] / cnt;
    float var  = stats[256 + o] / cnt - mean * mean;
    float a = gamma[o] * rsqrtf(var + EPS);
    coef[o] = a;
    coef[256 + o] = beta[o] - a * mean;
}

// ============================================================
// K4 v2 (pass 1): per (n,g):
//   - stage rel rows 0..7 in LDS (stride 256)
//   - build QEb[i][t], KEb[j][t] in bf16 (stride 136) via 8x8 register
//     patches (q from global+coef in regs, rel window from LDS in regs)
//   - qk = QE^T*KE via mfma_f32_16x16x32_bf16, store bf16 to global
//   - BN stats for qe/ke (fp32 pre-round) and qk via wave reduce + atomics
// LDS: 2*34816 + 8192 = 77824 B -> 2 WG/CU.
// ============================================================
__global__ __launch_bounds__(256, 2) void k4_pass1(
    const float* __restrict__ qkv, const float* __restrict__ rel,
    const float* __restrict__ cq, u16* __restrict__ qk,
    float* __restrict__ stats)
{
    __shared__ u16 QEb[128 * 136];
    __shared__ u16 KEb[128 * 136];
    __shared__ float relq[8 * 256];
    const int tid = threadIdx.x;
    const int n = blockIdx.x >> 4, g = blockIdx.x & 15;

    // stage rel (8 rows of 255) into LDS, stride 256
#pragma unroll
    for (int k = 0; k < 8; ++k) {
        int f = tid + k * 256;
        int row = f >> 8, d = f & 255;
        if (d < 255) relq[row * 256 + d] = rel[row * 255 + d];
    }
    __syncthreads();

    // ---------------- construction: 8x8 patches ----------------
    const int pt = tid & 15, pi = tid >> 4;
    const int t0 = pt * 8, i0 = pi * 8;
    const int d0 = t0 - i0 + 120;          // always in [0,240], multiple of 8

    float qes = 0.f, qesq = 0.f, kes = 0.f, kesq = 0.f;

#pragma unroll
    for (int mat = 0; mat < 2; ++mat) {
        // q (or k) rows in registers, normalized
        float qv[4][8];
#pragma unroll
        for (int c = 0; c < 4; ++c) {
            int o = g * 16 + mat * 4 + c;
            float a = cq[o], bb = cq[256 + o];
            const float* p = qkv + ((size_t)n * 256 + o) * 128 + t0;
            float4 x0 = *(const float4*)(p);
            float4 x1 = *(const float4*)(p + 4);
            qv[c][0] = a * x0.x + bb; qv[c][1] = a * x0.y + bb;
            qv[c][2] = a * x0.z + bb; qv[c][3] = a * x0.w + bb;
            qv[c][4] = a * x1.x + bb; qv[c][5] = a * x1.y + bb;
            qv[c][6] = a * x1.z + bb; qv[c][7] = a * x1.w + bb;
        }
        // rel window [d0, d0+16) for 4 rows
        float rr[4][16];
#pragma unroll
        for (int c = 0; c < 4; ++c) {
            const float* p = relq + (mat * 4 + c) * 256 + d0;
#pragma unroll
            for (int j = 0; j < 4; ++j) {
                float4 v = *(const float4*)(p + j * 4);
                rr[c][j*4+0] = v.x; rr[c][j*4+1] = v.y;
                rr[c][j*4+2] = v.z; rr[c][j*4+3] = v.w;
            }
        }
        u16* MB = mat ? KEb : QEb;
        float s = 0.f, sq = 0.f;
#pragma unroll
        for (int ii = 0; ii < 8; ++ii) {
            float vv[8];
#pragma unroll
            for (int tt = 0; tt < 8; ++tt) {
                float v = qv[0][tt] * rr[0][7 + tt - ii]
                        + qv[1][tt] * rr[1][7 + tt - ii]
                        + qv[2][tt] * rr[2][7 + tt - ii]
                        + qv[3][tt] * rr[3][7 + tt - ii];
                vv[tt] = v;
                s += v; sq = fmaf(v, v, sq);
            }
            uint4 w;
            w.x = pack2(vv[0], vv[1]); w.y = pack2(vv[2], vv[3]);
            w.z = pack2(vv[4], vv[5]); w.w = pack2(vv[6], vv[7]);
            *(uint4*)(MB + (i0 + ii) * 136 + t0) = w;
        }
        if (mat == 0) { qes = s; qesq = sq; } else { kes = s; kesq = sq; }
    }
    __syncthreads();

    // ---------------- MFMA matmul: qk = QE^T * KE ----------------
    const int lane = tid & 63, wv = tid >> 6;
    const int fm = lane & 15, fq = lane >> 4;

    f32x4 acc[2][8];
#pragma unroll
    for (int a = 0; a < 2; ++a)
#pragma unroll
        for (int b = 0; b < 8; ++b) acc[a][b] = (f32x4){0.f, 0.f, 0.f, 0.f};

#pragma unroll
    for (int kb = 0; kb < 4; ++kb) {
        const int ko = kb * 32 + fq * 8;
        bf16x8 a0 = *(const bf16x8*)(QEb + (wv * 32 + fm) * 136 + ko);
        bf16x8 a1 = *(const bf16x8*)(QEb + (wv * 32 + 16 + fm) * 136 + ko);
#pragma unroll
        for (int tj = 0; tj < 8; ++tj) {
            bf16x8 bfr = *(const bf16x8*)(KEb + (tj * 16 + fm) * 136 + ko);
            acc[0][tj] = __builtin_amdgcn_mfma_f32_16x16x32_bf16(a0, bfr, acc[0][tj], 0, 0, 0);
            acc[1][tj] = __builtin_amdgcn_mfma_f32_16x16x32_bf16(a1, bfr, acc[1][tj], 0, 0, 0);
        }
    }

    // epilogue: qk stats + bf16 store
    float qks = 0.f, qksq = 0.f;
    u16* qkg = qk + (size_t)(n * 16 + g) * 16384;
#pragma unroll
    for (int ti = 0; ti < 2; ++ti) {
#pragma unroll
        for (int tj = 0; tj < 8; ++tj) {
#pragma unroll
            for (int r = 0; r < 4; ++r) {
                float v = acc[ti][tj][r];
                qks += v; qksq = fmaf(v, v, qksq);
                int row = wv * 32 + ti * 16 + fq * 4 + r;
                qkg[row * 128 + tj * 16 + fm] = f2bf(v);
            }
        }
    }

    // wave reduce 6 stats, atomics from lane 0
#pragma unroll
    for (int m = 1; m < 64; m <<= 1) {
        qes += __shfl_xor(qes, m);  qesq += __shfl_xor(qesq, m);
        kes += __shfl_xor(kes, m);  kesq += __shfl_xor(kesq, m);
        qks += __shfl_xor(qks, m);  qksq += __shfl_xor(qksq, m);
    }
    if (lane == 0) {
        atomicAdd(&stats[512 + g], qks);       atomicAdd(&stats[560 + g], qksq);
        atomicAdd(&stats[512 + 16 + g], qes);  atomicAdd(&stats[560 + 16 + g], qesq);
        atomicAdd(&stats[512 + 32 + g], kes);  atomicAdd(&stats[560 + 32 + g], kesq);
    }
}

__global__ void k5_coef_sim(const float* __restrict__ stats,
                            const float* __restrict__ gamma, const float* __restrict__ beta,
                            float* __restrict__ coef)
{
    int ch = threadIdx.x;
    if (ch < 48) {
        const float cnt = 2097152.f;
        float mean = stats[512 + ch] / cnt;
        float var  = stats[560 + ch] / cnt - mean * mean;
        float a = gamma[ch] * rsqrtf(var + EPS);
        coef[ch] = a;
        coef[48 + ch] = beta[ch] - a * mean;
    }
}

// ============================================================
// K6 (pass 2): per (n,g): sim rows = a_qk*qk + a_qe*qe + a_ke*ke + b,
// softmax over j, am = P*v^T, ame = P (*) v_emb, write outraw + out stats.
// ============================================================
__global__ __launch_bounds__(256, 2) void k6_pass2(
    const float* __restrict__ qkv, const float* __restrict__ rel,
    const float* __restrict__ cq, const float* __restrict__ cs,
    const u16* __restrict__ qk,
    float* __restrict__ outraw, float* __restrict__ ostats)
{
    __shared__ float relT[255 * 20];
    __shared__ float qv_s[2048];
    __shared__ float ot_s[16 * 132];
    const int tid = threadIdx.x;
    const int n = blockIdx.x >> 4, g = blockIdx.x & 15;

#pragma unroll
    for (int k = 0; k < 16; ++k) {
        int f = tid + k * 256;
        int d = f >> 4, c = f & 15;
        if (d < 255) relT[d * 20 + c] = rel[c * 255 + d];
    }
#pragma unroll
    for (int k = 0; k < 8; ++k) {
        int f = tid + k * 256;
        int row = f >> 7, t = f & 127;
        int o = g * 16 + row;
        qv_s[f] = cq[o] * qkv[((size_t)n * 256 + o) * 128 + t] + cq[256 + o];
    }
    __syncthreads();

    const float aqk = cs[g], aqe = cs[16 + g], ake = cs[32 + g];
    const float bsum = cs[48 + g] + cs[64 + g] + cs[80 + g];
    const int lane = tid & 63, wv = tid >> 6;
    const int r = lane >> 4, q = lane & 15;

    float vreg[8][8];
#pragma unroll
    for (int jj = 0; jj < 8; ++jj) {
        int j = q + 16 * jj;
#pragma unroll
        for (int c = 0; c < 8; ++c) vreg[jj][c] = qv_s[1024 + c * 128 + j];
    }
    const u16* qkg = qk + (size_t)(n * 16 + g) * 16384;

    for (int it = 0; it < 8; ++it) {
        int i = wv * 32 + it * 4 + r;
        float q0 = qv_s[i], q1 = qv_s[128 + i], q2 = qv_s[256 + i], q3 = qv_s[384 + i];
        float k0 = qv_s[512 + i], k1 = qv_s[640 + i], k2 = qv_s[768 + i], k3 = qv_s[896 + i];
        const u16* qkrow = qkg + i * 128;
        float s[8]; float mx = -3.0e38f;
#pragma unroll
        for (int jj = 0; jj < 8; ++jj) {
            int j = q + 16 * jj;
            int d = i - j + 127;
            float4 rq = *(const float4*)(relT + d * 20);
            float4 rk = *(const float4*)(relT + d * 20 + 4);
            float qe = q0 * rq.x + q1 * rq.y + q2 * rq.z + q3 * rq.w;
            float ke = k0 * rk.x + k1 * rk.y + k2 * rk.z + k3 * rk.w;
            float qkf = bf2f(qkrow[j]);
            float sv = aqk * qkf + aqe * qe + ake * ke + bsum;
            s[jj] = sv; mx = fmaxf(mx, sv);
        }
#pragma unroll
        for (int m = 1; m < 16; m <<= 1) mx = fmaxf(mx, __shfl_xor(mx, m));
        float es = 0.f; float e[8];
#pragma unroll
        for (int jj = 0; jj < 8; ++jj) { e[jj] = __expf(s[jj] - mx); es += e[jj]; }
#pragma unroll
        for (int m = 1; m < 16; m <<= 1) es += __shfl_xor(es, m);

        float am[8], ame[8];
#pragma unroll
        for (int c = 0; c < 8; ++c) { am[c] = 0.f; ame[c] = 0.f; }
#pragma unroll
        for (int jj = 0; jj < 8; ++jj) {
            int d = i - (q + 16 * jj) + 127;
            float4 r0 = *(const float4*)(relT + d * 20 + 8);
            float4 r1 = *(const float4*)(relT + d * 20 + 12);
            float ej = e[jj];
#pragma unroll
            for (int c = 0; c < 8; ++c) am[c] += ej * vreg[jj][c];
            ame[0] += ej * r0.x; ame[1] += ej * r0.y; ame[2] += ej * r0.z; ame[3] += ej * r0.w;
            ame[4] += ej * r1.x; ame[5] += ej * r1.y; ame[6] += ej * r1.z; ame[7] += ej * r1.w;
        }
#pragma unroll
        for (int m = 1; m < 16; m <<= 1) {
#pragma unroll
            for (int c = 0; c < 8; ++c) {
                am[c]  += __shfl_xor(am[c], m);
                ame[c] += __shfl_xor(ame[c], m);
            }
        }
        float inv = 1.f / es;
        float sel = 0.f;
#pragma unroll
        for (int c = 0; c < 8; ++c) {
            sel = (q == c)     ? am[c]  : sel;
            sel = (q == c + 8) ? ame[c] : sel;
        }
        int ch16 = (q < 8) ? (2 * q) : (2 * (q - 8) + 1);
        ot_s[ch16 * 132 + i] = sel * inv;
    }
    __syncthreads();

#pragma unroll
    for (int k = 0; k < 8; ++k) {
        int f = tid + k * 256;
        int ch16 = f >> 7, i = f & 127;
        float v = ot_s[ch16 * 132 + i];
        outraw[((size_t)n * 256 + g * 16 + ch16) * 128 + i] = v;
        float sv = v, sq = v * v;
#pragma unroll
        for (int m = 1; m < 64; m <<= 1) { sv += __shfl_xor(sv, m); sq += __shfl_xor(sq, m); }
        if (lane == 0) {
            atomicAdd(&ostats[g * 16 + ch16], sv);
            atomicAdd(&ostats[256 + g * 16 + ch16], sq);
        }
    }
}

__global__ void k7_coef_out(const float* __restrict__ stats,
                            const float* __restrict__ gamma, const float* __restrict__ beta,
                            float* __restrict__ coef)
{
    int o = threadIdx.x;
    const float cnt = 16384.f;
    float mean = stats[608 + o] / cnt;
    float var  = stats[864 + o] / cnt - mean * mean;
    float a = gamma[o] * rsqrtf(var + EPS);
    coef[o] = a;
    coef[256 + o] = beta[o] - a * mean;
}

__global__ __launch_bounds__(256) void k8_final(
    const float* __restrict__ outraw, const float* __restrict__ co,
    float* __restrict__ out)
{
    int idx = blockIdx.x * 256 + threadIdx.x;
    int w  = idx & 127;
    int h  = (idx >> 7) & 63;
    int oc = (idx >> 13) & 127;
    int b  = idx >> 20;
    int n  = b * 64 + h;
    int o0 = oc * 2;
    float x0 = outraw[((size_t)n * 256 + o0) * 128 + w];
    float x1 = outraw[((size_t)n * 256 + o0 + 1) * 128 + w];
    out[idx] = (co[o0] * x0 + co[256 + o0]) + (co[o0 + 1] * x1 + co[256 + o0 + 1]);
}

// ============================================================
// Workspace layout (floats): see round-0 comment; unchanged.
// ============================================================
extern "C" void kernel_launch(void* const* d_in, const int* in_sizes, int n_in,
                              void* d_out, int out_size, void* d_ws, size_t ws_size,
                              hipStream_t stream)
{
    const float* x   = (const float*)d_in[0];
    const float* Wq  = (const float*)d_in[1];
    const float* gq  = (const float*)d_in[2];
    const float* bq  = (const float*)d_in[3];
    const float* rel = (const float*)d_in[4];
    const float* gs  = (const float*)d_in[5];
    const float* bs  = (const float*)d_in[6];
    const float* go  = (const float*)d_in[7];
    const float* bo  = (const float*)d_in[8];

    float* ws     = (float*)d_ws;
    float* qkv    = ws;
    float* outraw = ws + 4194304;
    u16*   qk     = (u16*)(ws + 8388608);
    float* stats  = ws + 25165824;
    float* cq     = stats + 1120;
    float* cs     = stats + 1632;
    float* co     = stats + 1728;

    (void)hipMemsetAsync(stats, 0, 1120 * sizeof(float), stream);

    k1_gemm_qkv<<<dim3(4, 128), 256, 0, stream>>>(x, Wq, qkv, stats);
    k3_coef_qkv<<<1, 256, 0, stream>>>(stats, gq, bq, cq);
    k4_pass1<<<2048, 256, 0, stream>>>(qkv, rel, cq, qk, stats);
    k5_coef_sim<<<1, 64, 0, stream>>>(stats, gs, bs, cs);
    k6_pass2<<<2048, 256, 0, stream>>>(qkv, rel, cq, cs, qk, outraw, stats + 608);
    k7_coef_out<<<1, 256, 0, stream>>>(stats, go, bo, co);
    k8_final<<<8192, 256, 0, stream>>>(outraw, co, (float*)d_out);
}

// Round 4
// 361.466 us; speedup vs baseline: 1.3488x; 1.3152x over previous
//
#include <hip/hip_runtime.h>

#define EPS 1e-5f
typedef unsigned short u16;
typedef unsigned int u32;

typedef __attribute__((ext_vector_type(8))) short bf16x8;
typedef __attribute__((ext_vector_type(4))) float f32x4;

// ---------- bf16 helpers ----------
__device__ __forceinline__ float bf2f(u16 h) {
    u32 u = ((u32)h) << 16;
    return __builtin_bit_cast(float, u);
}
__device__ __forceinline__ u16 f2bf(float f) {
    u32 u = __builtin_bit_cast(u32, f);
    u32 r = (u + 0x7fffu + ((u >> 16) & 1u)) >> 16;   // RNE
    return (u16)r;
}
__device__ __forceinline__ u32 pack2(float a, float b) {
    return (u32)f2bf(a) | ((u32)f2bf(b) << 16);
}

// ============================================================
// K1: qkv[n,o,l] = sum_c W[o,c] * x[b,c,h,l]   (n = b*64+h)
// ============================================================
__global__ __launch_bounds__(256) void k1_gemm_qkv(
    const float* __restrict__ x, const float* __restrict__ Wq,
    float* __restrict__ qkv, float* __restrict__ stats)
{
    __shared__ float Wt[64 * 68];
    __shared__ float xt[64 * 128];
    const int tid = threadIdx.x;
    const int ot = blockIdx.x;
    const int n  = blockIdx.y;
    const int b = n >> 6, h = n & 63;
    const int to = tid >> 5, tl = tid & 31;
    const int o0 = to * 8, l0 = tl * 4;

    float acc[8][4];
#pragma unroll
    for (int r = 0; r < 8; ++r) { acc[r][0]=0.f; acc[r][1]=0.f; acc[r][2]=0.f; acc[r][3]=0.f; }

    for (int cb = 0; cb < 128; cb += 64) {
        __syncthreads();
#pragma unroll
        for (int k = 0; k < 4; ++k) {
            int f = tid + k * 256;
            int oo = f >> 4, c4 = f & 15;
            float4 v = *(const float4*)(Wq + (ot * 64 + oo) * 128 + cb + c4 * 4);
            *(float4*)(Wt + oo * 68 + c4 * 4) = v;
        }
#pragma unroll
        for (int k = 0; k < 8; ++k) {
            int f = tid + k * 256;
            int c = f >> 5, l4 = f & 31;
            float4 v = *(const float4*)(x + ((size_t)((b * 128 + cb + c) * 64 + h)) * 128 + l4 * 4);
            *(float4*)(xt + c * 128 + l4 * 4) = v;
        }
        __syncthreads();
#pragma unroll 4
        for (int c = 0; c < 64; ++c) {
            float4 xv = *(const float4*)(xt + c * 128 + l0);
#pragma unroll
            for (int r = 0; r < 8; ++r) {
                float w = Wt[(o0 + r) * 68 + c];
                acc[r][0] += w * xv.x; acc[r][1] += w * xv.y;
                acc[r][2] += w * xv.z; acc[r][3] += w * xv.w;
            }
        }
    }

#pragma unroll
    for (int r = 0; r < 8; ++r) {
        int o = ot * 64 + o0 + r;
        *(float4*)(qkv + ((size_t)n * 256 + o) * 128 + l0) =
            make_float4(acc[r][0], acc[r][1], acc[r][2], acc[r][3]);
        float s  = acc[r][0] + acc[r][1] + acc[r][2] + acc[r][3];
        float sq = acc[r][0]*acc[r][0] + acc[r][1]*acc[r][1] + acc[r][2]*acc[r][2] + acc[r][3]*acc[r][3];
#pragma unroll
        for (int m = 1; m < 32; m <<= 1) {
            s  += __shfl_xor(s, m);
            sq += __shfl_xor(sq, m);
        }
        if (tl == 0) {
            atomicAdd(&stats[o], s);
            atomicAdd(&stats[256 + o], sq);
        }
    }
}

__global__ void k3_coef_qkv(const float* __restrict__ stats,
                            const float* __restrict__ gamma, const float* __restrict__ beta,
                            float* __restrict__ coef)
{
    int o = threadIdx.x;
    const float cnt = 16384.f;
    float mean = stats[o] / cnt;
    float var  = stats[256 + o] / cnt - mean * mean;
    float a = gamma[o] * rsqrtf(var + EPS);
    coef[o] = a;
    coef[256 + o] = beta[o] - a * mean;
}

// ============================================================
// K4 v3 (pass 1): 512 threads per (n,g).
//  - construction: 4(t)x8(i) patches, q + rel windows from global (L1-hot),
//    b64 LDS writes into QEb/KEb [128][136] bf16 (M[i][t] = QE[t,i]).
//  - MFMA: 8 waves, each a 16-row strip: qk = M_Q rows . M_K rows over t.
//  - epilogue: wave rewrites its own QEb strip with C (bf16), barrier,
//    coalesced uint4 stores; BN stats via wave reduce + atomics.
// LDS 70 KB -> 2 blocks/CU = 16 waves/CU.
// ============================================================
__global__ __launch_bounds__(512, 4) void k4_pass1(
    const float* __restrict__ qkv, const float* __restrict__ rel,
    const float* __restrict__ cq, u16* __restrict__ qk,
    float* __restrict__ stats)
{
    __shared__ u16 QEb[128 * 136];
    __shared__ u16 KEb[128 * 136];
    __shared__ float red[8 * 6];
    const int tid = threadIdx.x;
    const int n = blockIdx.x >> 4, g = blockIdx.x & 15;

    // ---------------- construction: 4x8 patches ----------------
    const int pt = tid & 31, pi = tid >> 5;
    const int t0 = pt * 4, i0 = pi * 8;
    const int d0 = t0 - i0 + 120;          // in [0,244], multiple of 4

    float qes = 0.f, qesq = 0.f, kes = 0.f, kesq = 0.f;

#pragma unroll
    for (int mat = 0; mat < 2; ++mat) {
        float qv[4][4];
#pragma unroll
        for (int c = 0; c < 4; ++c) {
            int o = g * 16 + mat * 4 + c;
            float a = cq[o], bb = cq[256 + o];
            float4 x0 = *(const float4*)(qkv + ((size_t)n * 256 + o) * 128 + t0);
            qv[c][0] = fmaf(a, x0.x, bb); qv[c][1] = fmaf(a, x0.y, bb);
            qv[c][2] = fmaf(a, x0.z, bb); qv[c][3] = fmaf(a, x0.w, bb);
        }
        float rr[4][12];
#pragma unroll
        for (int c = 0; c < 4; ++c) {
            const float* p = rel + (mat * 4 + c) * 255 + d0;
#pragma unroll
            for (int j = 0; j < 3; ++j) {
                float4 v = *(const float4*)(p + j * 4);
                rr[c][j*4+0] = v.x; rr[c][j*4+1] = v.y;
                rr[c][j*4+2] = v.z; rr[c][j*4+3] = v.w;
            }
        }
        u16* MB = mat ? KEb : QEb;
        float s = 0.f, sq = 0.f;
#pragma unroll
        for (int ii = 0; ii < 8; ++ii) {
            float vv[4];
#pragma unroll
            for (int tt = 0; tt < 4; ++tt) {
                int dl = tt - ii + 7;       // in [0,10]
                float v = qv[0][tt] * rr[0][dl] + qv[1][tt] * rr[1][dl]
                        + qv[2][tt] * rr[2][dl] + qv[3][tt] * rr[3][dl];
                vv[tt] = v;
                s += v; sq = fmaf(v, v, sq);
            }
            *(uint2*)(MB + (i0 + ii) * 136 + t0) =
                make_uint2(pack2(vv[0], vv[1]), pack2(vv[2], vv[3]));
        }
        if (mat == 0) { qes = s; qesq = sq; } else { kes = s; kesq = sq; }
    }
    __syncthreads();

    // ---------------- MFMA: 8 waves x 16-row strips ----------------
    const int lane = tid & 63, wv = tid >> 6;
    const int fm = lane & 15, fq = lane >> 4;

    f32x4 acc[8];
#pragma unroll
    for (int tj = 0; tj < 8; ++tj) acc[tj] = (f32x4){0.f, 0.f, 0.f, 0.f};

#pragma unroll
    for (int kb = 0; kb < 4; ++kb) {
        const int ko = kb * 32 + fq * 8;
        bf16x8 a0 = *(const bf16x8*)(QEb + (wv * 16 + fm) * 136 + ko);
#pragma unroll
        for (int tj = 0; tj < 8; ++tj) {
            bf16x8 bfr = *(const bf16x8*)(KEb + (tj * 16 + fm) * 136 + ko);
            acc[tj] = __builtin_amdgcn_mfma_f32_16x16x32_bf16(a0, bfr, acc[tj], 0, 0, 0);
        }
    }

    // epilogue: stats + C -> own QEb strip (bf16, row-major)
    float qks = 0.f, qksq = 0.f;
#pragma unroll
    for (int tj = 0; tj < 8; ++tj) {
#pragma unroll
        for (int r = 0; r < 4; ++r) {
            float v = acc[tj][r];
            qks += v; qksq = fmaf(v, v, qksq);
            QEb[(wv * 16 + fq * 4 + r) * 136 + tj * 16 + fm] = f2bf(v);
        }
    }

    // wave reduce 6 stats
#pragma unroll
    for (int m = 1; m < 64; m <<= 1) {
        qes += __shfl_xor(qes, m);  qesq += __shfl_xor(qesq, m);
        kes += __shfl_xor(kes, m);  kesq += __shfl_xor(kesq, m);
        qks += __shfl_xor(qks, m);  qksq += __shfl_xor(qksq, m);
    }
    if (lane == 0) {
        red[wv * 6 + 0] = qes; red[wv * 6 + 1] = qesq;
        red[wv * 6 + 2] = kes; red[wv * 6 + 3] = kesq;
        red[wv * 6 + 4] = qks; red[wv * 6 + 5] = qksq;
    }
    __syncthreads();

    // coalesced qk store: 512 threads x 4 uint4
    u16* qkg = qk + (size_t)(n * 16 + g) * 16384;
#pragma unroll
    for (int k = 0; k < 4; ++k) {
        int f = tid + k * 512;              // < 2048
        int row = f >> 4, c8 = f & 15;
        uint4 v = *(const uint4*)(QEb + row * 136 + c8 * 8);
        *(uint4*)(qkg + row * 128 + c8 * 8) = v;
    }

    if (tid < 6) {
        float tot = 0.f;
#pragma unroll
        for (int w = 0; w < 8; ++w) tot += red[w * 6 + tid];
        int off = (tid & 1) ? 560 : 512;
        int ch = (tid < 2) ? (16 + g) : (tid < 4) ? (32 + g) : g;
        atomicAdd(&stats[off + ch], tot);
    }
}

__global__ void k5_coef_sim(const float* __restrict__ stats,
                            const float* __restrict__ gamma, const float* __restrict__ beta,
                            float* __restrict__ coef)
{
    int ch = threadIdx.x;
    if (ch < 48) {
        const float cnt = 2097152.f;
        float mean = stats[512 + ch] / cnt;
        float var  = stats[560 + ch] / cnt - mean * mean;
        float a = gamma[ch] * rsqrtf(var + EPS);
        coef[ch] = a;
        coef[48 + ch] = beta[ch] - a * mean;
    }
}

// ============================================================
// K6 (pass 2): per (n,g): sim = a_qk*qk + a_qe*qe + a_ke*ke + b,
// softmax, am = P*v^T, ame = P (*) v_emb, outraw + out stats.
// LDS 37 KB -> 4 blocks/CU (launch_bounds (256,4) -> 16 waves/CU).
// ============================================================
__global__ __launch_bounds__(256, 4) void k6_pass2(
    const float* __restrict__ qkv, const float* __restrict__ rel,
    const float* __restrict__ cq, const float* __restrict__ cs,
    const u16* __restrict__ qk,
    float* __restrict__ outraw, float* __restrict__ ostats)
{
    __shared__ float relT[255 * 20];
    __shared__ float qv_s[2048];
    __shared__ float ot_s[16 * 132];
    const int tid = threadIdx.x;
    const int n = blockIdx.x >> 4, g = blockIdx.x & 15;

#pragma unroll
    for (int k = 0; k < 16; ++k) {
        int f = tid + k * 256;
        int d = f >> 4, c = f & 15;
        if (d < 255) relT[d * 20 + c] = rel[c * 255 + d];
    }
#pragma unroll
    for (int k = 0; k < 8; ++k) {
        int f = tid + k * 256;
        int row = f >> 7, t = f & 127;
        int o = g * 16 + row;
        qv_s[f] = cq[o] * qkv[((size_t)n * 256 + o) * 128 + t] + cq[256 + o];
    }
    __syncthreads();

    const float aqk = cs[g], aqe = cs[16 + g], ake = cs[32 + g];
    const float bsum = cs[48 + g] + cs[64 + g] + cs[80 + g];
    const int lane = tid & 63, wv = tid >> 6;
    const int r = lane >> 4, q = lane & 15;

    float vreg[8][8];
#pragma unroll
    for (int jj = 0; jj < 8; ++jj) {
        int j = q + 16 * jj;
#pragma unroll
        for (int c = 0; c < 8; ++c) vreg[jj][c] = qv_s[1024 + c * 128 + j];
    }
    const u16* qkg = qk + (size_t)(n * 16 + g) * 16384;

    for (int it = 0; it < 8; ++it) {
        int i = wv * 32 + it * 4 + r;
        float q0 = qv_s[i], q1 = qv_s[128 + i], q2 = qv_s[256 + i], q3 = qv_s[384 + i];
        float k0 = qv_s[512 + i], k1 = qv_s[640 + i], k2 = qv_s[768 + i], k3 = qv_s[896 + i];
        const u16* qkrow = qkg + i * 128;
        float s[8]; float mx = -3.0e38f;
#pragma unroll
        for (int jj = 0; jj < 8; ++jj) {
            int j = q + 16 * jj;
            int d = i - j + 127;
            float4 rq = *(const float4*)(relT + d * 20);
            float4 rk = *(const float4*)(relT + d * 20 + 4);
            float qe = q0 * rq.x + q1 * rq.y + q2 * rq.z + q3 * rq.w;
            float ke = k0 * rk.x + k1 * rk.y + k2 * rk.z + k3 * rk.w;
            float qkf = bf2f(qkrow[j]);
            float sv = aqk * qkf + aqe * qe + ake * ke + bsum;
            s[jj] = sv; mx = fmaxf(mx, sv);
        }
#pragma unroll
        for (int m = 1; m < 16; m <<= 1) mx = fmaxf(mx, __shfl_xor(mx, m));
        float es = 0.f; float e[8];
#pragma unroll
        for (int jj = 0; jj < 8; ++jj) { e[jj] = __expf(s[jj] - mx); es += e[jj]; }
#pragma unroll
        for (int m = 1; m < 16; m <<= 1) es += __shfl_xor(es, m);

        float am[8], ame[8];
#pragma unroll
        for (int c = 0; c < 8; ++c) { am[c] = 0.f; ame[c] = 0.f; }
#pragma unroll
        for (int jj = 0; jj < 8; ++jj) {
            int d = i - (q + 16 * jj) + 127;
            float4 r0 = *(const float4*)(relT + d * 20 + 8);
            float4 r1 = *(const float4*)(relT + d * 20 + 12);
            float ej = e[jj];
#pragma unroll
            for (int c = 0; c < 8; ++c) am[c] += ej * vreg[jj][c];
            ame[0] += ej * r0.x; ame[1] += ej * r0.y; ame[2] += ej * r0.z; ame[3] += ej * r0.w;
            ame[4] += ej * r1.x; ame[5] += ej * r1.y; ame[6] += ej * r1.z; ame[7] += ej * r1.w;
        }
#pragma unroll
        for (int m = 1; m < 16; m <<= 1) {
#pragma unroll
            for (int c = 0; c < 8; ++c) {
                am[c]  += __shfl_xor(am[c], m);
                ame[c] += __shfl_xor(ame[c], m);
            }
        }
        float inv = 1.f / es;
        float sel = 0.f;
#pragma unroll
        for (int c = 0; c < 8; ++c) {
            sel = (q == c)     ? am[c]  : sel;
            sel = (q == c + 8) ? ame[c] : sel;
        }
        int ch16 = (q < 8) ? (2 * q) : (2 * (q - 8) + 1);
        ot_s[ch16 * 132 + i] = sel * inv;
    }
    __syncthreads();

#pragma unroll
    for (int k = 0; k < 8; ++k) {
        int f = tid + k * 256;
        int ch16 = f >> 7, i = f & 127;
        float v = ot_s[ch16 * 132 + i];
        outraw[((size_t)n * 256 + g * 16 + ch16) * 128 + i] = v;
        float sv = v, sq = v * v;
#pragma unroll
        for (int m = 1; m < 64; m <<= 1) { sv += __shfl_xor(sv, m); sq += __shfl_xor(sq, m); }
        if (lane == 0) {
            atomicAdd(&ostats[g * 16 + ch16], sv);
            atomicAdd(&ostats[256 + g * 16 + ch16], sq);
        }
    }
}

__global__ void k7_coef_out(const float* __restrict__ stats,
                            const float* __restrict__ gamma, const float* __restrict__ beta,
                            float* __restrict__ coef)
{
    int o = threadIdx.x;
    const float cnt = 16384.f;
    float mean = stats[608 + o] / cnt;
    float var  = stats[864 + o] / cnt - mean * mean;
    float a = gamma[o] * rsqrtf(var + EPS);
    coef[o] = a;
    coef[256 + o] = beta[o] - a * mean;
}

__global__ __launch_bounds__(256) void k8_final(
    const float* __restrict__ outraw, const float* __restrict__ co,
    float* __restrict__ out)
{
    int idx = blockIdx.x * 256 + threadIdx.x;
    int w  = idx & 127;
    int h  = (idx >> 7) & 63;
    int oc = (idx >> 13) & 127;
    int b  = idx >> 20;
    int n  = b * 64 + h;
    int o0 = oc * 2;
    float x0 = outraw[((size_t)n * 256 + o0) * 128 + w];
    float x1 = outraw[((size_t)n * 256 + o0 + 1) * 128 + w];
    out[idx] = (co[o0] * x0 + co[256 + o0]) + (co[o0 + 1] * x1 + co[256 + o0 + 1]);
}

// ============================================================
// Workspace layout (floats): unchanged from round 0.
// ============================================================
extern "C" void kernel_launch(void* const* d_in, const int* in_sizes, int n_in,
                              void* d_out, int out_size, void* d_ws, size_t ws_size,
                              hipStream_t stream)
{
    const float* x   = (const float*)d_in[0];
    const float* Wq  = (const float*)d_in[1];
    const float* gq  = (const float*)d_in[2];
    const float* bq  = (const float*)d_in[3];
    const float* rel = (const float*)d_in[4];
    const float* gs  = (const float*)d_in[5];
    const float* bs  = (const float*)d_in[6];
    const float* go  = (const float*)d_in[7];
    const float* bo  = (const float*)d_in[8];

    float* ws     = (float*)d_ws;
    float* qkv    = ws;
    float* outraw = ws + 4194304;
    u16*   qk     = (u16*)(ws + 8388608);
    float* stats  = ws + 25165824;
    float* cq     = stats + 1120;
    float* cs     = stats + 1632;
    float* co     = stats + 1728;

    (void)hipMemsetAsync(stats, 0, 1120 * sizeof(float), stream);

    k1_gemm_qkv<<<dim3(4, 128), 256, 0, stream>>>(x, Wq, qkv, stats);
    k3_coef_qkv<<<1, 256, 0, stream>>>(stats, gq, bq, cq);
    k4_pass1<<<2048, 512, 0, stream>>>(qkv, rel, cq, qk, stats);
    k5_coef_sim<<<1, 64, 0, stream>>>(stats, gs, bs, cs);
    k6_pass2<<<2048, 256, 0, stream>>>(qkv, rel, cq, cs, qk, outraw, stats + 608);
    k7_coef_out<<<1, 256, 0, stream>>>(stats, go, bo, co);
    k8_final<<<8192, 256, 0, stream>>>(outraw, co, (float*)d_out);
}

// Round 5
// 345.936 us; speedup vs baseline: 1.4094x; 1.0449x over previous
//
#include <hip/hip_runtime.h>

#define EPS 1e-5f
typedef unsigned short u16;
typedef unsigned int u32;

typedef __attribute__((ext_vector_type(8))) short bf16x8;
typedef __attribute__((ext_vector_type(4))) float f32x4;

// ---------- bf16 helpers ----------
__device__ __forceinline__ float bf2f(u16 h) {
    u32 u = ((u32)h) << 16;
    return __builtin_bit_cast(float, u);
}
__device__ __forceinline__ u16 f2bf(float f) {
    u32 u = __builtin_bit_cast(u32, f);
    u32 r = (u + 0x7fffu + ((u >> 16) & 1u)) >> 16;   // RNE
    return (u16)r;
}
__device__ __forceinline__ u32 pack2(float a, float b) {
    return (u32)f2bf(a) | ((u32)f2bf(b) << 16);
}

// ============================================================
// K1: qkv[n,o,l] = sum_c W[o,c] * x[b,c,h,l]   (n = b*64+h)
// ============================================================
__global__ __launch_bounds__(256) void k1_gemm_qkv(
    const float* __restrict__ x, const float* __restrict__ Wq,
    float* __restrict__ qkv, float* __restrict__ stats)
{
    __shared__ float Wt[64 * 68];
    __shared__ float xt[64 * 128];
    const int tid = threadIdx.x;
    const int ot = blockIdx.x;
    const int n  = blockIdx.y;
    const int b = n >> 6, h = n & 63;
    const int to = tid >> 5, tl = tid & 31;
    const int o0 = to * 8, l0 = tl * 4;

    float acc[8][4];
#pragma unroll
    for (int r = 0; r < 8; ++r) { acc[r][0]=0.f; acc[r][1]=0.f; acc[r][2]=0.f; acc[r][3]=0.f; }

    for (int cb = 0; cb < 128; cb += 64) {
        __syncthreads();
#pragma unroll
        for (int k = 0; k < 4; ++k) {
            int f = tid + k * 256;
            int oo = f >> 4, c4 = f & 15;
            float4 v = *(const float4*)(Wq + (ot * 64 + oo) * 128 + cb + c4 * 4);
            *(float4*)(Wt + oo * 68 + c4 * 4) = v;
        }
#pragma unroll
        for (int k = 0; k < 8; ++k) {
            int f = tid + k * 256;
            int c = f >> 5, l4 = f & 31;
            float4 v = *(const float4*)(x + ((size_t)((b * 128 + cb + c) * 64 + h)) * 128 + l4 * 4);
            *(float4*)(xt + c * 128 + l4 * 4) = v;
        }
        __syncthreads();
#pragma unroll 4
        for (int c = 0; c < 64; ++c) {
            float4 xv = *(const float4*)(xt + c * 128 + l0);
#pragma unroll
            for (int r = 0; r < 8; ++r) {
                float w = Wt[(o0 + r) * 68 + c];
                acc[r][0] += w * xv.x; acc[r][1] += w * xv.y;
                acc[r][2] += w * xv.z; acc[r][3] += w * xv.w;
            }
        }
    }

#pragma unroll
    for (int r = 0; r < 8; ++r) {
        int o = ot * 64 + o0 + r;
        *(float4*)(qkv + ((size_t)n * 256 + o) * 128 + l0) =
            make_float4(acc[r][0], acc[r][1], acc[r][2], acc[r][3]);
        float s  = acc[r][0] + acc[r][1] + acc[r][2] + acc[r][3];
        float sq = acc[r][0]*acc[r][0] + acc[r][1]*acc[r][1] + acc[r][2]*acc[r][2] + acc[r][3]*acc[r][3];
#pragma unroll
        for (int m = 1; m < 32; m <<= 1) {
            s  += __shfl_xor(s, m);
            sq += __shfl_xor(sq, m);
        }
        if (tl == 0) {
            atomicAdd(&stats[o], s);
            atomicAdd(&stats[256 + o], sq);
        }
    }
}

__global__ void k3_coef_qkv(const float* __restrict__ stats,
                            const float* __restrict__ gamma, const float* __restrict__ beta,
                            float* __restrict__ coef)
{
    int o = threadIdx.x;
    const float cnt = 16384.f;
    float mean = stats[o] / cnt;
    float var  = stats[256 + o] / cnt - mean * mean;
    float a = gamma[o] * rsqrtf(var + EPS);
    coef[o] = a;
    coef[256 + o] = beta[o] - a * mean;
}

// ============================================================
// K4 v3 (pass 1): unchanged from round 4 (512 thr, MFMA).
// ============================================================
__global__ __launch_bounds__(512, 4) void k4_pass1(
    const float* __restrict__ qkv, const float* __restrict__ rel,
    const float* __restrict__ cq, u16* __restrict__ qk,
    float* __restrict__ stats)
{
    __shared__ u16 QEb[128 * 136];
    __shared__ u16 KEb[128 * 136];
    __shared__ float red[8 * 6];
    const int tid = threadIdx.x;
    const int n = blockIdx.x >> 4, g = blockIdx.x & 15;

    const int pt = tid & 31, pi = tid >> 5;
    const int t0 = pt * 4, i0 = pi * 8;
    const int d0 = t0 - i0 + 120;

    float qes = 0.f, qesq = 0.f, kes = 0.f, kesq = 0.f;

#pragma unroll
    for (int mat = 0; mat < 2; ++mat) {
        float qv[4][4];
#pragma unroll
        for (int c = 0; c < 4; ++c) {
            int o = g * 16 + mat * 4 + c;
            float a = cq[o], bb = cq[256 + o];
            float4 x0 = *(const float4*)(qkv + ((size_t)n * 256 + o) * 128 + t0);
            qv[c][0] = fmaf(a, x0.x, bb); qv[c][1] = fmaf(a, x0.y, bb);
            qv[c][2] = fmaf(a, x0.z, bb); qv[c][3] = fmaf(a, x0.w, bb);
        }
        float rr[4][12];
#pragma unroll
        for (int c = 0; c < 4; ++c) {
            const float* p = rel + (mat * 4 + c) * 255 + d0;
#pragma unroll
            for (int j = 0; j < 3; ++j) {
                float4 v = *(const float4*)(p + j * 4);
                rr[c][j*4+0] = v.x; rr[c][j*4+1] = v.y;
                rr[c][j*4+2] = v.z; rr[c][j*4+3] = v.w;
            }
        }
        u16* MB = mat ? KEb : QEb;
        float s = 0.f, sq = 0.f;
#pragma unroll
        for (int ii = 0; ii < 8; ++ii) {
            float vv[4];
#pragma unroll
            for (int tt = 0; tt < 4; ++tt) {
                int dl = tt - ii + 7;
                float v = qv[0][tt] * rr[0][dl] + qv[1][tt] * rr[1][dl]
                        + qv[2][tt] * rr[2][dl] + qv[3][tt] * rr[3][dl];
                vv[tt] = v;
                s += v; sq = fmaf(v, v, sq);
            }
            *(uint2*)(MB + (i0 + ii) * 136 + t0) =
                make_uint2(pack2(vv[0], vv[1]), pack2(vv[2], vv[3]));
        }
        if (mat == 0) { qes = s; qesq = sq; } else { kes = s; kesq = sq; }
    }
    __syncthreads();

    const int lane = tid & 63, wv = tid >> 6;
    const int fm = lane & 15, fq = lane >> 4;

    f32x4 acc[8];
#pragma unroll
    for (int tj = 0; tj < 8; ++tj) acc[tj] = (f32x4){0.f, 0.f, 0.f, 0.f};

#pragma unroll
    for (int kb = 0; kb < 4; ++kb) {
        const int ko = kb * 32 + fq * 8;
        bf16x8 a0 = *(const bf16x8*)(QEb + (wv * 16 + fm) * 136 + ko);
#pragma unroll
        for (int tj = 0; tj < 8; ++tj) {
            bf16x8 bfr = *(const bf16x8*)(KEb + (tj * 16 + fm) * 136 + ko);
            acc[tj] = __builtin_amdgcn_mfma_f32_16x16x32_bf16(a0, bfr, acc[tj], 0, 0, 0);
        }
    }

    float qks = 0.f, qksq = 0.f;
#pragma unroll
    for (int tj = 0; tj < 8; ++tj) {
#pragma unroll
        for (int r = 0; r < 4; ++r) {
            float v = acc[tj][r];
            qks += v; qksq = fmaf(v, v, qksq);
            QEb[(wv * 16 + fq * 4 + r) * 136 + tj * 16 + fm] = f2bf(v);
        }
    }

#pragma unroll
    for (int m = 1; m < 64; m <<= 1) {
        qes += __shfl_xor(qes, m);  qesq += __shfl_xor(qesq, m);
        kes += __shfl_xor(kes, m);  kesq += __shfl_xor(kesq, m);
        qks += __shfl_xor(qks, m);  qksq += __shfl_xor(qksq, m);
    }
    if (lane == 0) {
        red[wv * 6 + 0] = qes; red[wv * 6 + 1] = qesq;
        red[wv * 6 + 2] = kes; red[wv * 6 + 3] = kesq;
        red[wv * 6 + 4] = qks; red[wv * 6 + 5] = qksq;
    }
    __syncthreads();

    u16* qkg = qk + (size_t)(n * 16 + g) * 16384;
#pragma unroll
    for (int k = 0; k < 4; ++k) {
        int f = tid + k * 512;
        int row = f >> 4, c8 = f & 15;
        uint4 v = *(const uint4*)(QEb + row * 136 + c8 * 8);
        *(uint4*)(qkg + row * 128 + c8 * 8) = v;
    }

    if (tid < 6) {
        float tot = 0.f;
#pragma unroll
        for (int w = 0; w < 8; ++w) tot += red[w * 6 + tid];
        int off = (tid & 1) ? 560 : 512;
        int ch = (tid < 2) ? (16 + g) : (tid < 4) ? (32 + g) : g;
        atomicAdd(&stats[off + ch], tot);
    }
}

__global__ void k5_coef_sim(const float* __restrict__ stats,
                            const float* __restrict__ gamma, const float* __restrict__ beta,
                            float* __restrict__ coef)
{
    int ch = threadIdx.x;
    if (ch < 48) {
        const float cnt = 2097152.f;
        float mean = stats[512 + ch] / cnt;
        float var  = stats[560 + ch] / cnt - mean * mean;
        float a = gamma[ch] * rsqrtf(var + EPS);
        coef[ch] = a;
        coef[48 + ch] = beta[ch] - a * mean;
    }
}

// ============================================================
// K6 v2 (pass 2): ROW-PER-LANE online softmax. 128 threads per (n,g),
// lane = row i. No cross-lane softmax/PV reductions.
//  LDS: relb[d][16ch] bf16 stride 24 (q:0-3, k:4-7, v-emb:8-15),
//       vb[j][8ch] bf16 stride 8 (broadcast reads, j wave-uniform),
//       qn_s[8][128] fp32 (q,k rows).
//  Per element: 1 b128 (rel qk-chs) + 1 b128 (rel v-chs) + 1 b128 (v)
//  + 16 bf16 qk row chunk from global (per-lane contiguous).
// ~18.5 KB LDS, 8 blocks/CU, 16 waves/CU.
// ============================================================
__global__ __launch_bounds__(128, 4) void k6_pass2(
    const float* __restrict__ qkv, const float* __restrict__ rel,
    const float* __restrict__ cq, const float* __restrict__ cs,
    const u16* __restrict__ qk,
    float* __restrict__ outraw, float* __restrict__ ostats)
{
    __shared__ u16 relb[256 * 24];     // [d][ch], d<255
    __shared__ u16 vb[128 * 8];        // [j][c]
    __shared__ float qn_s[8 * 128];    // q rows 0..3, k rows 4..7 (normalized)
    const int tid = threadIdx.x;       // 0..127 = row i
    const int n = blockIdx.x >> 4, g = blockIdx.x & 15;

    // stage relb: 16 ch x 255 d
#pragma unroll
    for (int k = 0; k < 32; ++k) {
        int f = tid + k * 128;          // < 4096
        int c = f >> 8, d = f & 255;
        if (d < 255) relb[d * 24 + c] = f2bf(rel[c * 255 + d]);
    }
    // stage qn_s (q,k normalized fp32)
#pragma unroll
    for (int k = 0; k < 8; ++k) {
        int f = tid + k * 128;          // < 1024
        int c = f >> 7, t = f & 127;
        int o = g * 16 + c;
        qn_s[f] = fmaf(cq[o], qkv[((size_t)n * 256 + o) * 128 + t], cq[256 + o]);
    }
    // stage vb (v normalized bf16)
#pragma unroll
    for (int k = 0; k < 8; ++k) {
        int f = tid + k * 128;          // < 1024
        int c = f >> 7, j = f & 127;
        int o = g * 16 + 8 + c;
        float v = fmaf(cq[o], qkv[((size_t)n * 256 + o) * 128 + j], cq[256 + o]);
        vb[j * 8 + c] = f2bf(v);
    }
    __syncthreads();

    const float aqk = cs[g], aqe = cs[16 + g], ake = cs[32 + g];
    const float bsum = cs[48 + g] + cs[64 + g] + cs[80 + g];
    const int i = tid;

    float q0 = qn_s[i],       q1 = qn_s[128 + i], q2 = qn_s[256 + i], q3 = qn_s[384 + i];
    float k0 = qn_s[512 + i], k1 = qn_s[640 + i], k2 = qn_s[768 + i], k3 = qn_s[896 + i];

    const u16* qkrow = qk + (size_t)(n * 16 + g) * 16384 + i * 128;

    float m = -3.0e38f, l = 0.f;
    float am[8], ame[8];
#pragma unroll
    for (int c = 0; c < 8; ++c) { am[c] = 0.f; ame[c] = 0.f; }

#pragma unroll
    for (int jc = 0; jc < 8; ++jc) {
        // qk chunk (16 bf16, per-lane contiguous, 16B aligned)
        union { uint4 v[2]; u16 h[16]; } qh;
        qh.v[0] = *(const uint4*)(qkrow + jc * 16);
        qh.v[1] = *(const uint4*)(qkrow + jc * 16 + 8);

        const int dbase = i + 127 - jc * 16;
        float s[16]; float mc = -3.0e38f;
#pragma unroll
        for (int jl = 0; jl < 16; ++jl) {
            int d = dbase - jl;
            bf16x8 rb = *(const bf16x8*)(relb + d * 24);
            float qe = q0 * bf2f((u16)rb[0]) + q1 * bf2f((u16)rb[1])
                     + q2 * bf2f((u16)rb[2]) + q3 * bf2f((u16)rb[3]);
            float ke = k0 * bf2f((u16)rb[4]) + k1 * bf2f((u16)rb[5])
                     + k2 * bf2f((u16)rb[6]) + k3 * bf2f((u16)rb[7]);
            float sv = aqk * bf2f(qh.h[jl]) + aqe * qe + ake * ke + bsum;
            s[jl] = sv; mc = fmaxf(mc, sv);
        }
        float mn = fmaxf(m, mc);
        float sc = __expf(m - mn);
        l *= sc;
#pragma unroll
        for (int c = 0; c < 8; ++c) { am[c] *= sc; ame[c] *= sc; }
        m = mn;
#pragma unroll
        for (int jl = 0; jl < 16; ++jl) {
            float e = __expf(s[jl] - m);
            l += e;
            int j = jc * 16 + jl;
            bf16x8 vv = *(const bf16x8*)(vb + j * 8);               // broadcast
            bf16x8 rv = *(const bf16x8*)(relb + (dbase - jl) * 24 + 8);
#pragma unroll
            for (int c = 0; c < 8; ++c) {
                am[c]  = fmaf(e, bf2f((u16)vv[c]), am[c]);
                ame[c] = fmaf(e, bf2f((u16)rv[c]), ame[c]);
            }
        }
    }

    // epilogue: normalize, write out, BN stats
    float inv = 1.f / l;
    float o16[16];
#pragma unroll
    for (int c = 0; c < 8; ++c) { o16[2 * c] = am[c] * inv; o16[2 * c + 1] = ame[c] * inv; }

    float* orow = outraw + ((size_t)n * 256 + g * 16) * 128 + i;
#pragma unroll
    for (int c16 = 0; c16 < 16; ++c16) orow[c16 * 128] = o16[c16];

    const int lane = tid & 63;
#pragma unroll
    for (int c16 = 0; c16 < 16; ++c16) {
        float sv = o16[c16], sq = o16[c16] * o16[c16];
#pragma unroll
        for (int mm = 1; mm < 64; mm <<= 1) { sv += __shfl_xor(sv, mm); sq += __shfl_xor(sq, mm); }
        if (lane == 0) {
            atomicAdd(&ostats[g * 16 + c16], sv);
            atomicAdd(&ostats[256 + g * 16 + c16], sq);
        }
    }
}

__global__ void k7_coef_out(const float* __restrict__ stats,
                            const float* __restrict__ gamma, const float* __restrict__ beta,
                            float* __restrict__ coef)
{
    int o = threadIdx.x;
    const float cnt = 16384.f;
    float mean = stats[608 + o] / cnt;
    float var  = stats[864 + o] / cnt - mean * mean;
    float a = gamma[o] * rsqrtf(var + EPS);
    coef[o] = a;
    coef[256 + o] = beta[o] - a * mean;
}

__global__ __launch_bounds__(256) void k8_final(
    const float* __restrict__ outraw, const float* __restrict__ co,
    float* __restrict__ out)
{
    int idx = blockIdx.x * 256 + threadIdx.x;
    int w  = idx & 127;
    int h  = (idx >> 7) & 63;
    int oc = (idx >> 13) & 127;
    int b  = idx >> 20;
    int n  = b * 64 + h;
    int o0 = oc * 2;
    float x0 = outraw[((size_t)n * 256 + o0) * 128 + w];
    float x1 = outraw[((size_t)n * 256 + o0 + 1) * 128 + w];
    out[idx] = (co[o0] * x0 + co[256 + o0]) + (co[o0 + 1] * x1 + co[256 + o0 + 1]);
}

// ============================================================
// Workspace layout (floats): unchanged from round 0.
// ============================================================
extern "C" void kernel_launch(void* const* d_in, const int* in_sizes, int n_in,
                              void* d_out, int out_size, void* d_ws, size_t ws_size,
                              hipStream_t stream)
{
    const float* x   = (const float*)d_in[0];
    const float* Wq  = (const float*)d_in[1];
    const float* gq  = (const float*)d_in[2];
    const float* bq  = (const float*)d_in[3];
    const float* rel = (const float*)d_in[4];
    const float* gs  = (const float*)d_in[5];
    const float* bs  = (const float*)d_in[6];
    const float* go  = (const float*)d_in[7];
    const float* bo  = (const float*)d_in[8];

    float* ws     = (float*)d_ws;
    float* qkv    = ws;
    float* outraw = ws + 4194304;
    u16*   qk     = (u16*)(ws + 8388608);
    float* stats  = ws + 25165824;
    float* cq     = stats + 1120;
    float* cs     = stats + 1632;
    float* co     = stats + 1728;

    (void)hipMemsetAsync(stats, 0, 1120 * sizeof(float), stream);

    k1_gemm_qkv<<<dim3(4, 128), 256, 0, stream>>>(x, Wq, qkv, stats);
    k3_coef_qkv<<<1, 256, 0, stream>>>(stats, gq, bq, cq);
    k4_pass1<<<2048, 512, 0, stream>>>(qkv, rel, cq, qk, stats);
    k5_coef_sim<<<1, 64, 0, stream>>>(stats, gs, bs, cs);
    k6_pass2<<<2048, 128, 0, stream>>>(qkv, rel, cq, cs, qk, outraw, stats + 608);
    k7_coef_out<<<1, 256, 0, stream>>>(stats, go, bo, co);
    k8_final<<<8192, 256, 0, stream>>>(outraw, co, (float*)d_out);
}